// Round 1
// 399.249 us; speedup vs baseline: 1.0368x; 1.0368x over previous
//
#include <hip/hip_runtime.h>
#include <hip/hip_bf16.h>
#include <hip/hip_fp16.h>

#define N_NODES 100000
#define N_EDGES 800000
#define N_GRAPHS 512
#define D 128
#define EPSV 1e-5f

// radix-bucket CSR build params (256-node buckets)
#define NBLK 256
#define EPB  3125
#define NBUK 391          // ceil(100000/256)
#define MAXB 3072

// MFMA GEMM LDS layout (dwords): Ah 64 rows x 68dw, Wt2 128 cols x 68dw
#define LSTR 68
#define WOFF 4352

#define NSLOT 128         // stats scatter slots (6250 blocks / 128 ~ 49 per slot)
#define NPW 4             // nodes per wave in k_agg (block covers 16 nodes)

typedef _Float16 half8 __attribute__((ext_vector_type(8)));
typedef float floatx16 __attribute__((ext_vector_type(16)));

__device__ __forceinline__ float relu_f(float x){ return fmaxf(x, 0.0f); }

// inclusive scan of sd[0..511] with 256 threads
__device__ __forceinline__ void scan512(int* sd, int t)
{
    for (int off = 1; off < 512; off <<= 1){
        int i2 = t + 256;
        int v1 = (t  >= off) ? sd[t  - off] : 0;
        int v2 = (i2 >= off) ? sd[i2 - off] : 0;
        __syncthreads();
        sd[t]  += v1;
        sd[i2] += v2;
        __syncthreads();
    }
}

// ---------------- FRONT: p1 histogram (blocks 0..255) | wprep+zero+gstart ------
__global__ __launch_bounds__(256) void k_front(const int* __restrict__ dst,
                                               int* __restrict__ blockHist,
                                               const float* __restrict__ Ws,
                                               unsigned int* __restrict__ wpack,
                                               unsigned int* __restrict__ zbase,
                                               int zn,
                                               const int* __restrict__ batch,
                                               int* __restrict__ gstart,
                                               int* __restrict__ row_ptr)
{
    __shared__ int h[NBUK];
    int j = blockIdx.x, t = threadIdx.x;
    if (j < NBLK){
        for (int u = t; u < NBUK; u += 256) h[u] = 0;
        __syncthreads();
        int e0 = j * EPB;
        for (int e = e0 + t; e < e0 + EPB; e += 256)
            atomicAdd(&h[dst[e] >> 8], 1);
        __syncthreads();
        for (int u = t; u < NBUK; u += 256) blockHist[j * NBUK + u] = h[u];
    } else {
        int b = j - NBLK;                 // 0..95
        int idx = b * 256 + t;
        if (idx == 0){
            row_ptr[N_NODES] = N_EDGES;
            gstart[N_GRAPHS] = N_NODES;
        }
        if (idx < 3 * 128 * 64){
            int l  = idx >> 13;
            int r  = idx & 8191;
            int c  = r >> 6;
            int k2 = r & 63;
            const float* W = Ws + l * D * D;
            __half2 hh = __floats2half2_rn(W[(size_t)(2 * k2) * D + c],
                                           W[(size_t)(2 * k2 + 1) * D + c]);
            wpack[idx] = *(unsigned int*)&hh;
        }
        int stride = 96 * 256;
        for (int i = idx; i < zn; i += stride) zbase[i] = 0u;
        if (idx < N_GRAPHS){
            int g = idx;
            int lo = 0, hi = N_NODES;
            while (lo < hi){ int m = (lo + hi) >> 1; if (batch[m] < g) lo = m + 1; else hi = m; }
            gstart[g] = lo;
        }
    }
}

// ---------------- P2a: per-bucket column scan (NBUK blocks, parallel) ----------
__global__ __launch_bounds__(256) void k_p2a(const int* __restrict__ blockHist,
                                             int* __restrict__ colScan,
                                             int* __restrict__ bucketTotal)
{
    __shared__ int sd[256];
    int b = blockIdx.x, t = threadIdx.x;
    int v = blockHist[t * NBUK + b];
    sd[t] = v;
    __syncthreads();
    for (int off = 1; off < 256; off <<= 1){
        int u = (t >= off) ? sd[t - off] : 0;
        __syncthreads();
        sd[t] += u;
        __syncthreads();
    }
    colScan[t * NBUK + b] = sd[t] - v;
    if (t == 255) bucketTotal[b] = sd[255];
}

// ---------------- P3: scatter edges into bucket-sorted ebuf (LDS cursors) ------
__global__ __launch_bounds__(256) void k_p3(const int* __restrict__ src,
                                            const int* __restrict__ dst,
                                            const int* __restrict__ colScan,
                                            const int* __restrict__ bucketTotal,
                                            int2* __restrict__ ebuf)
{
    __shared__ int sd[512];
    __shared__ int cur[NBUK];
    int j = blockIdx.x, t = threadIdx.x;
    int i2 = t + 256;
    sd[t]  = (t  < NBUK) ? bucketTotal[t]  : 0;
    sd[i2] = (i2 < NBUK) ? bucketTotal[i2] : 0;
    __syncthreads();
    scan512(sd, t);
    if (t < NBUK)
        cur[t]  = (sd[t]  - bucketTotal[t])  + colScan[j * NBUK + t];
    if (i2 < NBUK)
        cur[i2] = (sd[i2] - bucketTotal[i2]) + colScan[j * NBUK + i2];
    __syncthreads();
    int e0 = j * EPB;
    for (int e = e0 + t; e < e0 + EPB; e += 256){
        int s = src[e], d = dst[e];
        int pos = atomicAdd(&cur[d >> 8], 1);
        int2 v; v.x = s; v.y = d;
        ebuf[pos] = v;
    }
}

// ---------------- P4: per-bucket counting sort -> row_ptr, csr_src, dinv, selfw
__global__ __launch_bounds__(256) void k_p4(const int2* __restrict__ ebuf,
                                            const int* __restrict__ bucketTotal,
                                            int* __restrict__ row_ptr,
                                            int* __restrict__ csr_src,
                                            float* __restrict__ dinv,
                                            float* __restrict__ selfw)
{
    __shared__ int2 stash[MAXB];
    __shared__ int sdScan[512];
    __shared__ int bins[256];
    __shared__ int sd[256];
    int b = blockIdx.x, t = threadIdx.x;
    int i2 = t + 256;
    sdScan[t]  = (t  < NBUK) ? bucketTotal[t]  : 0;
    sdScan[i2] = (i2 < NBUK) ? bucketTotal[i2] : 0;
    __syncthreads();
    scan512(sdScan, t);
    int cntb = bucketTotal[b];
    int base = sdScan[b] - cntb;
    bool st = (cntb <= MAXB);
    bins[t] = 0;
    __syncthreads();
    for (int i = t; i < cntb; i += 256){
        int2 ed = ebuf[base + i];
        if (st) stash[i] = ed;
        atomicAdd(&bins[ed.y & 255], 1);
    }
    __syncthreads();
    int a0 = bins[t];
    sd[t] = a0;
    __syncthreads();
    for (int off = 1; off < 256; off <<= 1){
        int v = (t >= off) ? sd[t - off] : 0;
        __syncthreads();
        sd[t] += v;
        __syncthreads();
    }
    int pex = sd[t] - a0;
    int node = b * 256 + t;
    if (node < N_NODES){
        row_ptr[node] = base + pex;
        float d = (float)(a0 + 1);
        dinv[node]  = rsqrtf(d);
        selfw[node] = 1.0f / d;
    }
    __syncthreads();
    bins[t] = pex;
    __syncthreads();
    for (int i = t; i < cntb; i += 256){
        int2 ed = st ? stash[i] : ebuf[base + i];
        int pos = atomicAdd(&bins[ed.y & 255], 1);
        csr_src[base + pos] = ed.x;
    }
}

// ---------------- MFMA GEMM v2: A staged via LDS (coalesced), W prepacked ------
__global__ __launch_bounds__(256) void k_gemm(const float* __restrict__ A,
                                              const unsigned int* __restrict__ wp,
                                              const float* __restrict__ scale,
                                              const float* __restrict__ shift,
                                              __half* __restrict__ outh,
                                              int useBn)
{
    __shared__ unsigned int lds32[WOFF + 128 * LSTR];   // 52224 B
    int tid = threadIdx.x;
    int rowBase = blockIdx.x * 64;

    #pragma unroll
    for (int rep = 0; rep < 8; rep++){
        int f  = rep * 256 + tid;
        int m  = f >> 5;
        int c4 = f & 31;
        int row = rowBase + m;
        if (row >= N_NODES) row = N_NODES - 1;
        float4 v = *(const float4*)(A + (size_t)row * D + c4 * 4);
        if (useBn){
            float4 sc = *(const float4*)(scale + c4 * 4);
            float4 sh = *(const float4*)(shift + c4 * 4);
            v.x = relu_f(fmaf(v.x, sc.x, sh.x));
            v.y = relu_f(fmaf(v.y, sc.y, sh.y));
            v.z = relu_f(fmaf(v.z, sc.z, sh.z));
            v.w = relu_f(fmaf(v.w, sc.w, sh.w));
        }
        __half2 h0 = __floats2half2_rn(v.x, v.y);
        __half2 h1 = __floats2half2_rn(v.z, v.w);
        uint2 u; u.x = *(unsigned int*)&h0; u.y = *(unsigned int*)&h1;
        *(uint2*)&lds32[m * LSTR + 2 * c4] = u;
    }
    {
        const uint4* gw = (const uint4*)wp;
        #pragma unroll
        for (int rep = 0; rep < 8; rep++){
            int f = rep * 256 + tid;
            int c = f >> 4;
            int q = f & 15;
            uint4 v = gw[f];
            *(uint4*)&lds32[WOFF + c * LSTR + 4 * q] = v;
        }
    }
    __syncthreads();

    int lane = tid & 63, wv = tid >> 6;
    int quad = lane >> 5;
    int ml   = (lane & 31) + (wv & 1) * 32;
    int cA   = (wv >> 1) * 64;
    int c0   = cA + (lane & 31);
    int c1   = c0 + 32;
    const unsigned int* aRow  = lds32 + ml * LSTR;
    const unsigned int* bRow0 = lds32 + WOFF + c0 * LSTR;
    const unsigned int* bRow1 = lds32 + WOFF + c1 * LSTR;
    floatx16 acc0 = {};
    floatx16 acc1 = {};
    #pragma unroll
    for (int ch = 0; ch < 8; ch++){
        int o = ch * 8 + quad * 4;
        half8 af = *(const half8*)(aRow  + o);
        half8 b0 = *(const half8*)(bRow0 + o);
        half8 b1 = *(const half8*)(bRow1 + o);
        acc0 = __builtin_amdgcn_mfma_f32_32x32x16_f16(af, b0, acc0, 0, 0, 0);
        acc1 = __builtin_amdgcn_mfma_f32_32x32x16_f16(af, b1, acc1, 0, 0, 0);
    }
    int rBase = rowBase + (wv & 1) * 32 + 4 * quad;
    #pragma unroll
    for (int r = 0; r < 16; r++){
        int outRow = rBase + (r & 3) + 8 * (r >> 2);
        if (outRow < N_NODES){
            outh[(size_t)outRow * D + c0] = __float2half(acc0[r]);
            outh[(size_t)outRow * D + c1] = __float2half(acc1[r]);
        }
    }
}

// ---------------- edge aggregation + bias + slot-scattered BN stats ------------
// v3: NPW consecutive nodes per wave (fully unrolled -> static reg indexing),
// stats accumulate in registers across nodes; ONE barrier + ONE atomic set per
// block (16 nodes) instead of per 4 nodes -> atomic WRITE traffic /4, barrier
// slack amortized, longer sustained gather phase per wave.
__global__ __launch_bounds__(256) void k_agg(const __half* __restrict__ t,
                                             const int* __restrict__ row_ptr,
                                             const int* __restrict__ csr_src,
                                             const float* __restrict__ dinv,
                                             const float* __restrict__ selfw,
                                             const float* __restrict__ bias,
                                             float* __restrict__ outb,
                                             float* __restrict__ Spart,
                                             float* __restrict__ Qpart)
{
    __shared__ float ldsS[4][128];
    __shared__ float ldsQ[4][128];
    int lane = threadIdx.x & 63;
    int wv   = threadIdx.x >> 6;
    int base = blockIdx.x * (4 * NPW) + wv * NPW;   // 4 waves x NPW nodes
    const __half2* t2 = (const __half2*)t;
    float2 b2 = ((const float2*)bias)[lane];
    float sa0 = 0.f, sa1 = 0.f, qa0 = 0.f, qa1 = 0.f;

    #pragma unroll
    for (int n = 0; n < NPW; n++){
        int i = base + n;
        int p0 = row_ptr[i], pe = row_ptr[i + 1];
        float sw  = selfw[i];
        float dvi = dinv[i];
        float2 a = __half22float2(t2[(size_t)i * 64 + lane]);
        float ax = a.x * sw, ay = a.y * sw;
        int p = p0;
        for (; p + 8 <= pe; p += 8){
            int s[8];
            #pragma unroll
            for (int j = 0; j < 8; j++) s[j] = csr_src[p + j];
            __half2 v[8];
            #pragma unroll
            for (int j = 0; j < 8; j++) v[j] = t2[(size_t)s[j] * 64 + lane];  // issue gathers first
            float w8[8];
            #pragma unroll
            for (int j = 0; j < 8; j++) w8[j] = dinv[s[j]] * dvi;
            #pragma unroll
            for (int j = 0; j < 8; j++){
                float2 f = __half22float2(v[j]);
                ax = fmaf(w8[j], f.x, ax);
                ay = fmaf(w8[j], f.y, ay);
            }
        }
        for (; p + 4 <= pe; p += 4){
            int s0 = csr_src[p], s1 = csr_src[p+1], s2 = csr_src[p+2], s3 = csr_src[p+3];
            __half2 v0 = t2[(size_t)s0 * 64 + lane];
            __half2 v1 = t2[(size_t)s1 * 64 + lane];
            __half2 v2 = t2[(size_t)s2 * 64 + lane];
            __half2 v3 = t2[(size_t)s3 * 64 + lane];
            float w0 = dinv[s0] * dvi, w1 = dinv[s1] * dvi;
            float w2 = dinv[s2] * dvi, w3 = dinv[s3] * dvi;
            float2 f0 = __half22float2(v0);
            float2 f1 = __half22float2(v1);
            float2 f2 = __half22float2(v2);
            float2 f3 = __half22float2(v3);
            ax = fmaf(w0, f0.x, ax); ay = fmaf(w0, f0.y, ay);
            ax = fmaf(w1, f1.x, ax); ay = fmaf(w1, f1.y, ay);
            ax = fmaf(w2, f2.x, ax); ay = fmaf(w2, f2.y, ay);
            ax = fmaf(w3, f3.x, ax); ay = fmaf(w3, f3.y, ay);
        }
        for (; p < pe; ++p){
            int s = csr_src[p];
            __half2 vv = t2[(size_t)s * 64 + lane];
            float w = dinv[s] * dvi;
            float2 f = __half22float2(vv);
            ax = fmaf(w, f.x, ax);
            ay = fmaf(w, f.y, ay);
        }
        ax += b2.x; ay += b2.y;
        float2 o; o.x = ax; o.y = ay;
        ((float2*)outb)[(size_t)i * 64 + lane] = o;
        sa0 += ax;               sa1 += ay;
        qa0 = fmaf(ax, ax, qa0); qa1 = fmaf(ay, ay, qa1);
    }

    ldsS[wv][2 * lane] = sa0;  ldsS[wv][2 * lane + 1] = sa1;
    ldsQ[wv][2 * lane] = qa0;  ldsQ[wv][2 * lane + 1] = qa1;
    __syncthreads();
    int tid = threadIdx.x;
    int slotBase = (blockIdx.x & (NSLOT - 1)) * 128;
    if (tid < 128){
        float s = ldsS[0][tid] + ldsS[1][tid] + ldsS[2][tid] + ldsS[3][tid];
        atomicAdd(&Spart[slotBase + tid], s);
    } else {
        int f = tid - 128;
        float q = ldsQ[0][f] + ldsQ[1][f] + ldsQ[2][f] + ldsQ[3][f];
        atomicAdd(&Qpart[slotBase + f], q);
    }
}

// ---------------- finalize: reduce NSLOT slots -> scale/shift (1 block) --------
__global__ __launch_bounds__(256) void k_fin2(const float* __restrict__ Spart,
                                              const float* __restrict__ Qpart,
                                              const float* __restrict__ gamma,
                                              const float* __restrict__ beta,
                                              float* __restrict__ sc,
                                              float* __restrict__ sh)
{
    int t = threadIdx.x;
    int f = t & 127;
    const float* src = (t < 128) ? Spart : Qpart;
    float acc = 0.f;
    for (int s2 = 0; s2 < NSLOT; s2++)
        acc += src[s2 * 128 + f];
    __shared__ float red[256];
    red[t] = acc;
    __syncthreads();
    if (t < 128){
        float Sv = red[t];
        float Qv = red[t + 128];
        float mean = Sv * (1.0f / N_NODES);
        float var  = fmaxf(Qv * (1.0f / N_NODES) - mean * mean, 0.0f);
        float inv  = rsqrtf(var + EPSV);
        float gm = gamma[f] * inv;
        sc[f] = gm;
        sh[f] = beta[f] - mean * gm;
    }
}

// ---------------- TAIL: per-graph BN+ReLU+mean + MLP head (one block/graph) ----
__global__ __launch_bounds__(256) void k_tail(const float* __restrict__ h,
                                              const int* __restrict__ gstart,
                                              const float* __restrict__ sc,
                                              const float* __restrict__ sh,
                                              const float* __restrict__ W1,
                                              const float* __restrict__ b1,
                                              const float* __restrict__ W2,
                                              const float* __restrict__ b2,
                                              float* __restrict__ out)
{
    __shared__ float part[256];
    __shared__ float z[128];
    __shared__ float red[128];
    int g = blockIdx.x;
    int tid = threadIdx.x;
    int f = tid & 127;
    int hf = tid >> 7;                // 0/1: row-parity split
    int s0 = gstart[g], s1 = gstart[g + 1];
    float scv = sc[f], shv = sh[f];
    float acc = 0.f;
    for (int i = s0 + hf; i < s1; i += 2)
        acc += relu_f(fmaf(h[(size_t)i * D + f], scv, shv));
    part[tid] = acc;
    __syncthreads();
    if (tid < 128){
        float c = fmaxf((float)(s1 - s0), 1.0f);
        z[f] = (part[f] + part[f + 128]) / c;
    }
    __syncthreads();
    // head GEMV: thread (f,hf) covers k in [hf*64, hf*64+64)
    float a = 0.f;
    int k0 = hf * 64;
    #pragma unroll 8
    for (int k = k0; k < k0 + 64; k++)
        a = fmaf(z[k], W1[k * D + f], a);
    part[tid] = a;
    __syncthreads();
    if (tid < 128){
        float av = relu_f(part[f] + part[f + 128] + b1[f]);
        red[f] = av * W2[f];
    }
    __syncthreads();
    for (int s2 = 64; s2 > 0; s2 >>= 1){
        if (tid < s2) red[tid] += red[tid + s2];
        __syncthreads();
    }
    if (tid == 0) out[g] = red[0] + b2[0];
}

extern "C" void kernel_launch(void* const* d_in, const int* in_sizes, int n_in,
                              void* d_out, int out_size, void* d_ws, size_t ws_size,
                              hipStream_t stream)
{
    const float* x      = (const float*)d_in[0];
    const int*   ei     = (const int*)d_in[1];
    const int*   batch  = (const int*)d_in[2];
    const float* Ws     = (const float*)d_in[3];
    const float* bs     = (const float*)d_in[4];
    const float* gammas = (const float*)d_in[5];
    const float* betas  = (const float*)d_in[6];
    const float* W1     = (const float*)d_in[7];
    const float* b1     = (const float*)d_in[8];
    const float* W2     = (const float*)d_in[9];
    const float* b2     = (const float*)d_in[10];
    float* out = (float*)d_out;

    const int* src = ei;
    const int* dst = ei + N_EDGES;

    char* w = (char*)d_ws;
    size_t off = 0;
    auto alloc = [&](size_t bytes) -> void* {
        void* p = w + off;
        off += (bytes + 255) & ~(size_t)255;
        return p;
    };
    int*   row_ptr     = (int*)  alloc((size_t)(N_NODES + 1) * 4);
    float* dinv        = (float*)alloc((size_t)N_NODES * 4);
    float* selfw       = (float*)alloc((size_t)N_NODES * 4);
    int*   csr_src     = (int*)  alloc((size_t)N_EDGES * 4);
    int*   blockHist   = (int*)  alloc((size_t)NBLK * NBUK * 4);
    int*   colScan     = (int*)  alloc((size_t)NBLK * NBUK * 4);
    int*   bucketTotal = (int*)  alloc((size_t)NBUK * 4);
    unsigned int* wpack = (unsigned int*)alloc((size_t)3 * 128 * 64 * 4);
    int*   gstart      = (int*)  alloc((size_t)(N_GRAPHS + 1) * 4);
    size_t zoff = off;                       // --- zero-span start ---
    float* stats       = (float*)alloc((size_t)3 * 2 * NSLOT * 128 * 4); // per layer: Spart, Qpart
    size_t zend = off;                       // --- zero-span end ---
    float* ssh         = (float*)alloc(3 * 256 * 4);   // per layer: scale, shift
    __half* tbuf       = (__half*)alloc((size_t)N_NODES * 128 * 2);  // fp16 gather table
    float* hbuf        = (float*)alloc((size_t)N_NODES * 128 * 4);   // fp32 h
    if (off > ws_size) return;

    // alias scratch (consumed before tbuf is first written; stream-ordered)
    int2* ebuf = (int2*)tbuf;    // 6.4 MB < 25.6 MB

    k_front<<<NBLK + 96, 256, 0, stream>>>(dst, blockHist, Ws, wpack,
                                           (unsigned int*)(w + zoff),
                                           (int)((zend - zoff) >> 2),
                                           batch, gstart, row_ptr);
    k_p2a<<<NBUK, 256, 0, stream>>>(blockHist, colScan, bucketTotal);
    k_p3 <<<NBLK, 256, 0, stream>>>(src, dst, colScan, bucketTotal, ebuf);
    k_p4 <<<NBUK, 256, 0, stream>>>(ebuf, bucketTotal, row_ptr, csr_src, dinv, selfw);

    const float* curIn = x;
    for (int l = 0; l < 3; l++){
        float* Sp = stats + (size_t)l * 2 * NSLOT * 128;
        float* Qp = Sp + NSLOT * 128;
        k_gemm<<<(N_NODES + 63) / 64, 256, 0, stream>>>(
            curIn, wpack + l * 8192,
            l ? ssh + (l - 1) * 256       : nullptr,
            l ? ssh + (l - 1) * 256 + 128 : nullptr,
            tbuf, l ? 1 : 0);
        k_agg<<<N_NODES / (4 * NPW), 256, 0, stream>>>(
            tbuf, row_ptr, csr_src, dinv, selfw,
            bs + l * 128, hbuf, Sp, Qp);
        k_fin2<<<1, 256, 0, stream>>>(
            Sp, Qp, gammas + l * 128, betas + l * 128,
            ssh + l * 256, ssh + l * 256 + 128);
        curIn = hbuf;
    }

    k_tail<<<N_GRAPHS, 256, 0, stream>>>(hbuf, gstart,
                                         ssh + 2 * 256, ssh + 2 * 256 + 128,
                                         W1, b1, W2, b2, out);
}

// Round 2
// 375.465 us; speedup vs baseline: 1.1025x; 1.0633x over previous
//
#include <hip/hip_runtime.h>
#include <hip/hip_bf16.h>
#include <hip/hip_fp16.h>

#define N_NODES 100000
#define N_EDGES 800000
#define N_GRAPHS 512
#define D 128
#define EPSV 1e-5f

// radix-bucket CSR build params (256-node buckets)
#define NBLK 256
#define EPB  3125
#define NBUK 391          // ceil(100000/256)
#define MAXB 3072

// MFMA GEMM LDS layout (dwords): Ah 64 rows x 68dw, Wt2 128 cols x 68dw
#define LSTR 68
#define WOFF 4352

#define NSLOT 128         // stats scatter slots (3125 blocks / 128 ~ 24 per slot)

typedef _Float16 half8 __attribute__((ext_vector_type(8)));
typedef float floatx16 __attribute__((ext_vector_type(16)));

__device__ __forceinline__ float relu_f(float x){ return fmaxf(x, 0.0f); }

// inclusive scan of sd[0..511] with 256 threads
__device__ __forceinline__ void scan512(int* sd, int t)
{
    for (int off = 1; off < 512; off <<= 1){
        int i2 = t + 256;
        int v1 = (t  >= off) ? sd[t  - off] : 0;
        int v2 = (i2 >= off) ? sd[i2 - off] : 0;
        __syncthreads();
        sd[t]  += v1;
        sd[i2] += v2;
        __syncthreads();
    }
}

// ---------------- FRONT: p1 histogram (blocks 0..255) | wprep+zero+gstart ------
__global__ __launch_bounds__(256) void k_front(const int* __restrict__ dst,
                                               int* __restrict__ blockHist,
                                               const float* __restrict__ Ws,
                                               unsigned int* __restrict__ wpack,
                                               unsigned int* __restrict__ zbase,
                                               int zn,
                                               const int* __restrict__ batch,
                                               int* __restrict__ gstart,
                                               int* __restrict__ row_ptr)
{
    __shared__ int h[NBUK];
    int j = blockIdx.x, t = threadIdx.x;
    if (j < NBLK){
        for (int u = t; u < NBUK; u += 256) h[u] = 0;
        __syncthreads();
        int e0 = j * EPB;
        for (int e = e0 + t; e < e0 + EPB; e += 256)
            atomicAdd(&h[dst[e] >> 8], 1);
        __syncthreads();
        for (int u = t; u < NBUK; u += 256) blockHist[j * NBUK + u] = h[u];
    } else {
        int b = j - NBLK;                 // 0..95
        int idx = b * 256 + t;
        if (idx == 0){
            row_ptr[N_NODES] = N_EDGES;
            gstart[N_GRAPHS] = N_NODES;
        }
        if (idx < 3 * 128 * 64){
            int l  = idx >> 13;
            int r  = idx & 8191;
            int c  = r >> 6;
            int k2 = r & 63;
            const float* W = Ws + l * D * D;
            __half2 hh = __floats2half2_rn(W[(size_t)(2 * k2) * D + c],
                                           W[(size_t)(2 * k2 + 1) * D + c]);
            wpack[idx] = *(unsigned int*)&hh;
        }
        int stride = 96 * 256;
        for (int i = idx; i < zn; i += stride) zbase[i] = 0u;
        if (idx < N_GRAPHS){
            int g = idx;
            int lo = 0, hi = N_NODES;
            while (lo < hi){ int m = (lo + hi) >> 1; if (batch[m] < g) lo = m + 1; else hi = m; }
            gstart[g] = lo;
        }
    }
}

// ---------------- P2a: per-bucket column scan (NBUK blocks, parallel) ----------
__global__ __launch_bounds__(256) void k_p2a(const int* __restrict__ blockHist,
                                             int* __restrict__ colScan,
                                             int* __restrict__ bucketTotal)
{
    __shared__ int sd[256];
    int b = blockIdx.x, t = threadIdx.x;
    int v = blockHist[t * NBUK + b];
    sd[t] = v;
    __syncthreads();
    for (int off = 1; off < 256; off <<= 1){
        int u = (t >= off) ? sd[t - off] : 0;
        __syncthreads();
        sd[t] += u;
        __syncthreads();
    }
    colScan[t * NBUK + b] = sd[t] - v;
    if (t == 255) bucketTotal[b] = sd[255];
}

// ---------------- P3: scatter edges into bucket-sorted ebuf (LDS cursors) ------
__global__ __launch_bounds__(256) void k_p3(const int* __restrict__ src,
                                            const int* __restrict__ dst,
                                            const int* __restrict__ colScan,
                                            const int* __restrict__ bucketTotal,
                                            int2* __restrict__ ebuf)
{
    __shared__ int sd[512];
    __shared__ int cur[NBUK];
    int j = blockIdx.x, t = threadIdx.x;
    int i2 = t + 256;
    sd[t]  = (t  < NBUK) ? bucketTotal[t]  : 0;
    sd[i2] = (i2 < NBUK) ? bucketTotal[i2] : 0;
    __syncthreads();
    scan512(sd, t);
    if (t < NBUK)
        cur[t]  = (sd[t]  - bucketTotal[t])  + colScan[j * NBUK + t];
    if (i2 < NBUK)
        cur[i2] = (sd[i2] - bucketTotal[i2]) + colScan[j * NBUK + i2];
    __syncthreads();
    int e0 = j * EPB;
    for (int e = e0 + t; e < e0 + EPB; e += 256){
        int s = src[e], d = dst[e];
        int pos = atomicAdd(&cur[d >> 8], 1);
        int2 v; v.x = s; v.y = d;
        ebuf[pos] = v;
    }
}

// ---------------- P4: per-bucket counting sort -> row_ptr, csr_src, dinv -------
__global__ __launch_bounds__(256) void k_p4(const int2* __restrict__ ebuf,
                                            const int* __restrict__ bucketTotal,
                                            int* __restrict__ row_ptr,
                                            int* __restrict__ csr_src,
                                            float* __restrict__ dinv)
{
    __shared__ int2 stash[MAXB];
    __shared__ int sdScan[512];
    __shared__ int bins[256];
    __shared__ int sd[256];
    int b = blockIdx.x, t = threadIdx.x;
    int i2 = t + 256;
    sdScan[t]  = (t  < NBUK) ? bucketTotal[t]  : 0;
    sdScan[i2] = (i2 < NBUK) ? bucketTotal[i2] : 0;
    __syncthreads();
    scan512(sdScan, t);
    int cntb = bucketTotal[b];
    int base = sdScan[b] - cntb;
    bool st = (cntb <= MAXB);
    bins[t] = 0;
    __syncthreads();
    for (int i = t; i < cntb; i += 256){
        int2 ed = ebuf[base + i];
        if (st) stash[i] = ed;
        atomicAdd(&bins[ed.y & 255], 1);
    }
    __syncthreads();
    int a0 = bins[t];
    sd[t] = a0;
    __syncthreads();
    for (int off = 1; off < 256; off <<= 1){
        int v = (t >= off) ? sd[t - off] : 0;
        __syncthreads();
        sd[t] += v;
        __syncthreads();
    }
    int pex = sd[t] - a0;
    int node = b * 256 + t;
    if (node < N_NODES){
        row_ptr[node] = base + pex;
        float d = (float)(a0 + 1);
        dinv[node]  = rsqrtf(d);
    }
    __syncthreads();
    bins[t] = pex;
    __syncthreads();
    for (int i = t; i < cntb; i += 256){
        int2 ed = st ? stash[i] : ebuf[base + i];
        int pos = atomicAdd(&bins[ed.y & 255], 1);
        csr_src[base + pos] = ed.x;
    }
}

// ---------------- MFMA GEMM: A staged via LDS, W prepacked, dinv-scaled out ----
// tbuf[row] = dinv[row] * (BN/ReLU(A[row]) @ W)  -- the dinv fold makes k_agg a
// pure unweighted gather-sum (self term: selfw*t = dinv*(dinv*t)).
__global__ __launch_bounds__(256) void k_gemm(const float* __restrict__ A,
                                              const unsigned int* __restrict__ wp,
                                              const float* __restrict__ scale,
                                              const float* __restrict__ shift,
                                              const float* __restrict__ dinv,
                                              __half* __restrict__ outh,
                                              int useBn)
{
    __shared__ unsigned int lds32[WOFF + 128 * LSTR];   // 52224 B
    int tid = threadIdx.x;
    int rowBase = blockIdx.x * 64;

    #pragma unroll
    for (int rep = 0; rep < 8; rep++){
        int f  = rep * 256 + tid;
        int m  = f >> 5;
        int c4 = f & 31;
        int row = rowBase + m;
        if (row >= N_NODES) row = N_NODES - 1;
        float4 v = *(const float4*)(A + (size_t)row * D + c4 * 4);
        if (useBn){
            float4 sc = *(const float4*)(scale + c4 * 4);
            float4 sh = *(const float4*)(shift + c4 * 4);
            v.x = relu_f(fmaf(v.x, sc.x, sh.x));
            v.y = relu_f(fmaf(v.y, sc.y, sh.y));
            v.z = relu_f(fmaf(v.z, sc.z, sh.z));
            v.w = relu_f(fmaf(v.w, sc.w, sh.w));
        }
        __half2 h0 = __floats2half2_rn(v.x, v.y);
        __half2 h1 = __floats2half2_rn(v.z, v.w);
        uint2 u; u.x = *(unsigned int*)&h0; u.y = *(unsigned int*)&h1;
        *(uint2*)&lds32[m * LSTR + 2 * c4] = u;
    }
    {
        const uint4* gw = (const uint4*)wp;
        #pragma unroll
        for (int rep = 0; rep < 8; rep++){
            int f = rep * 256 + tid;
            int c = f >> 4;
            int q = f & 15;
            uint4 v = gw[f];
            *(uint4*)&lds32[WOFF + c * LSTR + 4 * q] = v;
        }
    }
    __syncthreads();

    int lane = tid & 63, wv = tid >> 6;
    int quad = lane >> 5;
    int ml   = (lane & 31) + (wv & 1) * 32;
    int cA   = (wv >> 1) * 64;
    int c0   = cA + (lane & 31);
    int c1   = c0 + 32;
    const unsigned int* aRow  = lds32 + ml * LSTR;
    const unsigned int* bRow0 = lds32 + WOFF + c0 * LSTR;
    const unsigned int* bRow1 = lds32 + WOFF + c1 * LSTR;
    floatx16 acc0 = {};
    floatx16 acc1 = {};
    #pragma unroll
    for (int ch = 0; ch < 8; ch++){
        int o = ch * 8 + quad * 4;
        half8 af = *(const half8*)(aRow  + o);
        half8 b0 = *(const half8*)(bRow0 + o);
        half8 b1 = *(const half8*)(bRow1 + o);
        acc0 = __builtin_amdgcn_mfma_f32_32x32x16_f16(af, b0, acc0, 0, 0, 0);
        acc1 = __builtin_amdgcn_mfma_f32_32x32x16_f16(af, b1, acc1, 0, 0, 0);
    }
    int rBase = rowBase + (wv & 1) * 32 + 4 * quad;
    #pragma unroll
    for (int r = 0; r < 16; r++){
        int outRow = rBase + (r & 3) + 8 * (r >> 2);
        if (outRow < N_NODES){
            float dv = dinv[outRow];
            outh[(size_t)outRow * D + c0] = __float2half(acc0[r] * dv);
            outh[(size_t)outRow * D + c1] = __float2half(acc1[r] * dv);
        }
    }
}

__device__ __forceinline__ void accum8(float* acc, uint4 v)
{
    float2 f0 = __half22float2(*(__half2*)&v.x);
    float2 f1 = __half22float2(*(__half2*)&v.y);
    float2 f2 = __half22float2(*(__half2*)&v.z);
    float2 f3 = __half22float2(*(__half2*)&v.w);
    acc[0] += f0.x; acc[1] += f0.y; acc[2] += f1.x; acc[3] += f1.y;
    acc[4] += f2.x; acc[5] += f2.y; acc[6] += f3.x; acc[7] += f3.y;
}

// ---------------- edge aggregation v5: 16-lane groups, 16B/lane gathers --------
// Wave = 4 groups x 16 lanes. Group owns node i; lane q covers features
// [8q,8q+8). One edge row = ONE global_load_dwordx4 per group -> 4 edges per
// wave VMEM instruction (was 1 edge + dinv gather per edge). tbuf rows are
// pre-scaled by dinv[src] in k_gemm, so the sum is unweighted; final scale by
// dinv[i] + bias. Stats in regs, 2 shfl_xor rounds, slot-scattered atomics.
__global__ __launch_bounds__(256) void k_agg(const __half* __restrict__ t,
                                             const int* __restrict__ row_ptr,
                                             const int* __restrict__ csr_src,
                                             const float* __restrict__ dinv,
                                             const float* __restrict__ bias,
                                             float* __restrict__ outb,
                                             float* __restrict__ Spart,
                                             float* __restrict__ Qpart)
{
    __shared__ float ldsS[4][128];
    __shared__ float ldsQ[4][128];
    int tid  = threadIdx.x;
    int lane = tid & 63;
    int wv   = tid >> 6;
    int q    = lane & 15;          // feature slot
    int g    = lane >> 4;          // group 0..3
    const uint4* t4 = (const uint4*)t;
    float4* out4 = (float4*)outb;

    float4 bia = ((const float4*)bias)[2 * q];
    float4 bib = ((const float4*)bias)[2 * q + 1];

    float sa[8] = {0.f,0.f,0.f,0.f,0.f,0.f,0.f,0.f};
    float qa[8] = {0.f,0.f,0.f,0.f,0.f,0.f,0.f,0.f};

    int i0 = blockIdx.x * 32 + wv * 8 + g * 2;   // group covers 2 nodes

    for (int n = 0; n < 2; n++){
        int i  = i0 + n;
        int p  = row_ptr[i];
        int pe = row_ptr[i + 1];
        float acc[8];
        {   // self row (pre-scaled by dinv[i] already)
            uint4 v = t4[(size_t)i * 16 + q];
            float2 f0 = __half22float2(*(__half2*)&v.x);
            float2 f1 = __half22float2(*(__half2*)&v.y);
            float2 f2 = __half22float2(*(__half2*)&v.z);
            float2 f3 = __half22float2(*(__half2*)&v.w);
            acc[0] = f0.x; acc[1] = f0.y; acc[2] = f1.x; acc[3] = f1.y;
            acc[4] = f2.x; acc[5] = f2.y; acc[6] = f3.x; acc[7] = f3.y;
        }
        for (; p + 4 <= pe; p += 4){
            int s0 = csr_src[p],     s1 = csr_src[p + 1];
            int s2 = csr_src[p + 2], s3 = csr_src[p + 3];
            uint4 v0 = t4[(size_t)s0 * 16 + q];
            uint4 v1 = t4[(size_t)s1 * 16 + q];
            uint4 v2 = t4[(size_t)s2 * 16 + q];
            uint4 v3 = t4[(size_t)s3 * 16 + q];
            accum8(acc, v0); accum8(acc, v1); accum8(acc, v2); accum8(acc, v3);
        }
        for (; p < pe; ++p){
            int s = csr_src[p];
            uint4 v = t4[(size_t)s * 16 + q];
            accum8(acc, v);
        }
        float dvi = dinv[i];
        acc[0] = fmaf(acc[0], dvi, bia.x);
        acc[1] = fmaf(acc[1], dvi, bia.y);
        acc[2] = fmaf(acc[2], dvi, bia.z);
        acc[3] = fmaf(acc[3], dvi, bia.w);
        acc[4] = fmaf(acc[4], dvi, bib.x);
        acc[5] = fmaf(acc[5], dvi, bib.y);
        acc[6] = fmaf(acc[6], dvi, bib.z);
        acc[7] = fmaf(acc[7], dvi, bib.w);
        out4[(size_t)i * 32 + 2 * q]     = make_float4(acc[0], acc[1], acc[2], acc[3]);
        out4[(size_t)i * 32 + 2 * q + 1] = make_float4(acc[4], acc[5], acc[6], acc[7]);
        #pragma unroll
        for (int k = 0; k < 8; k++){
            sa[k] += acc[k];
            qa[k]  = fmaf(acc[k], acc[k], qa[k]);
        }
    }

    // combine the 4 groups' per-feature stats within the wave
    #pragma unroll
    for (int k = 0; k < 8; k++){
        sa[k] += __shfl_xor(sa[k], 16);
        sa[k] += __shfl_xor(sa[k], 32);
        qa[k] += __shfl_xor(qa[k], 16);
        qa[k] += __shfl_xor(qa[k], 32);
    }
    if (g == 0){
        #pragma unroll
        for (int k = 0; k < 8; k++){
            ldsS[wv][8 * q + k] = sa[k];
            ldsQ[wv][8 * q + k] = qa[k];
        }
    }
    __syncthreads();
    int slotBase = (blockIdx.x & (NSLOT - 1)) * 128;
    if (tid < 128){
        float s = ldsS[0][tid] + ldsS[1][tid] + ldsS[2][tid] + ldsS[3][tid];
        atomicAdd(&Spart[slotBase + tid], s);
    } else {
        int f = tid - 128;
        float qv = ldsQ[0][f] + ldsQ[1][f] + ldsQ[2][f] + ldsQ[3][f];
        atomicAdd(&Qpart[slotBase + f], qv);
    }
}

// ---------------- finalize: reduce NSLOT slots -> scale/shift (1 block) --------
__global__ __launch_bounds__(256) void k_fin2(const float* __restrict__ Spart,
                                              const float* __restrict__ Qpart,
                                              const float* __restrict__ gamma,
                                              const float* __restrict__ beta,
                                              float* __restrict__ sc,
                                              float* __restrict__ sh)
{
    int t = threadIdx.x;
    int f = t & 127;
    const float* src = (t < 128) ? Spart : Qpart;
    float acc = 0.f;
    for (int s2 = 0; s2 < NSLOT; s2++)
        acc += src[s2 * 128 + f];
    __shared__ float red[256];
    red[t] = acc;
    __syncthreads();
    if (t < 128){
        float Sv = red[t];
        float Qv = red[t + 128];
        float mean = Sv * (1.0f / N_NODES);
        float var  = fmaxf(Qv * (1.0f / N_NODES) - mean * mean, 0.0f);
        float inv  = rsqrtf(var + EPSV);
        float gm = gamma[f] * inv;
        sc[f] = gm;
        sh[f] = beta[f] - mean * gm;
    }
}

// ---------------- TAIL: per-graph BN+ReLU+mean + MLP head (one block/graph) ----
__global__ __launch_bounds__(256) void k_tail(const float* __restrict__ h,
                                              const int* __restrict__ gstart,
                                              const float* __restrict__ sc,
                                              const float* __restrict__ sh,
                                              const float* __restrict__ W1,
                                              const float* __restrict__ b1,
                                              const float* __restrict__ W2,
                                              const float* __restrict__ b2,
                                              float* __restrict__ out)
{
    __shared__ float part[256];
    __shared__ float z[128];
    __shared__ float red[128];
    int g = blockIdx.x;
    int tid = threadIdx.x;
    int f = tid & 127;
    int hf = tid >> 7;                // 0/1: row-parity split
    int s0 = gstart[g], s1 = gstart[g + 1];
    float scv = sc[f], shv = sh[f];
    float acc = 0.f;
    for (int i = s0 + hf; i < s1; i += 2)
        acc += relu_f(fmaf(h[(size_t)i * D + f], scv, shv));
    part[tid] = acc;
    __syncthreads();
    if (tid < 128){
        float c = fmaxf((float)(s1 - s0), 1.0f);
        z[f] = (part[f] + part[f + 128]) / c;
    }
    __syncthreads();
    // head GEMV: thread (f,hf) covers k in [hf*64, hf*64+64)
    float a = 0.f;
    int k0 = hf * 64;
    #pragma unroll 8
    for (int k = k0; k < k0 + 64; k++)
        a = fmaf(z[k], W1[k * D + f], a);
    part[tid] = a;
    __syncthreads();
    if (tid < 128){
        float av = relu_f(part[f] + part[f + 128] + b1[f]);
        red[f] = av * W2[f];
    }
    __syncthreads();
    for (int s2 = 64; s2 > 0; s2 >>= 1){
        if (tid < s2) red[tid] += red[tid + s2];
        __syncthreads();
    }
    if (tid == 0) out[g] = red[0] + b2[0];
}

extern "C" void kernel_launch(void* const* d_in, const int* in_sizes, int n_in,
                              void* d_out, int out_size, void* d_ws, size_t ws_size,
                              hipStream_t stream)
{
    const float* x      = (const float*)d_in[0];
    const int*   ei     = (const int*)d_in[1];
    const int*   batch  = (const int*)d_in[2];
    const float* Ws     = (const float*)d_in[3];
    const float* bs     = (const float*)d_in[4];
    const float* gammas = (const float*)d_in[5];
    const float* betas  = (const float*)d_in[6];
    const float* W1     = (const float*)d_in[7];
    const float* b1     = (const float*)d_in[8];
    const float* W2     = (const float*)d_in[9];
    const float* b2     = (const float*)d_in[10];
    float* out = (float*)d_out;

    const int* src = ei;
    const int* dst = ei + N_EDGES;

    char* w = (char*)d_ws;
    size_t off = 0;
    auto alloc = [&](size_t bytes) -> void* {
        void* p = w + off;
        off += (bytes + 255) & ~(size_t)255;
        return p;
    };
    int*   row_ptr     = (int*)  alloc((size_t)(N_NODES + 1) * 4);
    float* dinv        = (float*)alloc((size_t)N_NODES * 4);
    int*   csr_src     = (int*)  alloc((size_t)N_EDGES * 4);
    int*   blockHist   = (int*)  alloc((size_t)NBLK * NBUK * 4);
    int*   colScan     = (int*)  alloc((size_t)NBLK * NBUK * 4);
    int*   bucketTotal = (int*)  alloc((size_t)NBUK * 4);
    unsigned int* wpack = (unsigned int*)alloc((size_t)3 * 128 * 64 * 4);
    int*   gstart      = (int*)  alloc((size_t)(N_GRAPHS + 1) * 4);
    size_t zoff = off;                       // --- zero-span start ---
    float* stats       = (float*)alloc((size_t)3 * 2 * NSLOT * 128 * 4); // per layer: Spart, Qpart
    size_t zend = off;                       // --- zero-span end ---
    float* ssh         = (float*)alloc(3 * 256 * 4);   // per layer: scale, shift
    __half* tbuf       = (__half*)alloc((size_t)N_NODES * 128 * 2);  // fp16 gather table (dinv-scaled)
    float* hbuf        = (float*)alloc((size_t)N_NODES * 128 * 4);   // fp32 h
    if (off > ws_size) return;

    // alias scratch (consumed before tbuf is first written; stream-ordered)
    int2* ebuf = (int2*)tbuf;    // 6.4 MB < 25.6 MB

    k_front<<<NBLK + 96, 256, 0, stream>>>(dst, blockHist, Ws, wpack,
                                           (unsigned int*)(w + zoff),
                                           (int)((zend - zoff) >> 2),
                                           batch, gstart, row_ptr);
    k_p2a<<<NBUK, 256, 0, stream>>>(blockHist, colScan, bucketTotal);
    k_p3 <<<NBLK, 256, 0, stream>>>(src, dst, colScan, bucketTotal, ebuf);
    k_p4 <<<NBUK, 256, 0, stream>>>(ebuf, bucketTotal, row_ptr, csr_src, dinv);

    const float* curIn = x;
    for (int l = 0; l < 3; l++){
        float* Sp = stats + (size_t)l * 2 * NSLOT * 128;
        float* Qp = Sp + NSLOT * 128;
        k_gemm<<<(N_NODES + 63) / 64, 256, 0, stream>>>(
            curIn, wpack + l * 8192,
            l ? ssh + (l - 1) * 256       : nullptr,
            l ? ssh + (l - 1) * 256 + 128 : nullptr,
            dinv, tbuf, l ? 1 : 0);
        k_agg<<<N_NODES / 32, 256, 0, stream>>>(
            tbuf, row_ptr, csr_src, dinv,
            bs + l * 128, hbuf, Sp, Qp);
        k_fin2<<<1, 256, 0, stream>>>(
            Sp, Qp, gammas + l * 128, betas + l * 128,
            ssh + l * 256, ssh + l * 256 + 128);
        curIn = hbuf;
    }

    k_tail<<<N_GRAPHS, 256, 0, stream>>>(hbuf, gstart,
                                         ssh + 2 * 256, ssh + 2 * 256 + 128,
                                         W1, b1, W2, b2, out);
}

// Round 3
// 348.894 us; speedup vs baseline: 1.1865x; 1.0762x over previous
//
#include <hip/hip_runtime.h>
#include <hip/hip_bf16.h>
#include <hip/hip_fp16.h>

#define N_NODES 100000
#define N_EDGES 800000
#define N_GRAPHS 512
#define D 128
#define EPSV 1e-5f

// radix-bucket CSR build params (256-node buckets)
#define NBLK 256
#define EPB  3125
#define NBUK 391          // ceil(100000/256)
#define MAXB 3072

// MFMA GEMM LDS layout (dwords): Ah 64 rows x 68dw, Wt2 128 cols x 68dw
#define LSTR 68
#define WOFF 4352

#define NSLOT 128         // stats scatter slots (3125 blocks / 128 ~ 24 per slot)

typedef _Float16 half8 __attribute__((ext_vector_type(8)));
typedef float floatx16 __attribute__((ext_vector_type(16)));

__device__ __forceinline__ float relu_f(float x){ return fmaxf(x, 0.0f); }

// inclusive scan of sd[0..511] with 256 threads
__device__ __forceinline__ void scan512(int* sd, int t)
{
    for (int off = 1; off < 512; off <<= 1){
        int i2 = t + 256;
        int v1 = (t  >= off) ? sd[t  - off] : 0;
        int v2 = (i2 >= off) ? sd[i2 - off] : 0;
        __syncthreads();
        sd[t]  += v1;
        sd[i2] += v2;
        __syncthreads();
    }
}

// ---------------- FRONT: p1 histogram (blocks 0..255) | wprep+zero+gstart ------
__global__ __launch_bounds__(256) void k_front(const int* __restrict__ dst,
                                               int* __restrict__ blockHist,
                                               const float* __restrict__ Ws,
                                               unsigned int* __restrict__ wpack,
                                               unsigned int* __restrict__ zbase,
                                               int zn,
                                               const int* __restrict__ batch,
                                               int* __restrict__ gstart,
                                               int* __restrict__ row_ptr)
{
    __shared__ int h[NBUK];
    int j = blockIdx.x, t = threadIdx.x;
    if (j < NBLK){
        for (int u = t; u < NBUK; u += 256) h[u] = 0;
        __syncthreads();
        int e0 = j * EPB;
        for (int e = e0 + t; e < e0 + EPB; e += 256)
            atomicAdd(&h[dst[e] >> 8], 1);
        __syncthreads();
        for (int u = t; u < NBUK; u += 256) blockHist[j * NBUK + u] = h[u];
    } else {
        int b = j - NBLK;                 // 0..95
        int idx = b * 256 + t;
        if (idx == 0){
            row_ptr[N_NODES] = N_EDGES;
            gstart[N_GRAPHS] = N_NODES;
        }
        if (idx < 3 * 128 * 64){
            int l  = idx >> 13;
            int r  = idx & 8191;
            int c  = r >> 6;
            int k2 = r & 63;
            const float* W = Ws + l * D * D;
            __half2 hh = __floats2half2_rn(W[(size_t)(2 * k2) * D + c],
                                           W[(size_t)(2 * k2 + 1) * D + c]);
            wpack[idx] = *(unsigned int*)&hh;
        }
        int stride = 96 * 256;
        for (int i = idx; i < zn; i += stride) zbase[i] = 0u;
        if (idx < N_GRAPHS){
            int g = idx;
            int lo = 0, hi = N_NODES;
            while (lo < hi){ int m = (lo + hi) >> 1; if (batch[m] < g) lo = m + 1; else hi = m; }
            gstart[g] = lo;
        }
    }
}

// ---------------- P2a: per-bucket column scan (NBUK blocks, parallel) ----------
__global__ __launch_bounds__(256) void k_p2a(const int* __restrict__ blockHist,
                                             int* __restrict__ colScan,
                                             int* __restrict__ bucketTotal)
{
    __shared__ int sd[256];
    int b = blockIdx.x, t = threadIdx.x;
    int v = blockHist[t * NBUK + b];
    sd[t] = v;
    __syncthreads();
    for (int off = 1; off < 256; off <<= 1){
        int u = (t >= off) ? sd[t - off] : 0;
        __syncthreads();
        sd[t] += u;
        __syncthreads();
    }
    colScan[t * NBUK + b] = sd[t] - v;
    if (t == 255) bucketTotal[b] = sd[255];
}

// ---------------- P3: scatter edges into bucket-sorted ebuf (LDS cursors) ------
__global__ __launch_bounds__(256) void k_p3(const int* __restrict__ src,
                                            const int* __restrict__ dst,
                                            const int* __restrict__ colScan,
                                            const int* __restrict__ bucketTotal,
                                            int2* __restrict__ ebuf)
{
    __shared__ int sd[512];
    __shared__ int cur[NBUK];
    int j = blockIdx.x, t = threadIdx.x;
    int i2 = t + 256;
    sd[t]  = (t  < NBUK) ? bucketTotal[t]  : 0;
    sd[i2] = (i2 < NBUK) ? bucketTotal[i2] : 0;
    __syncthreads();
    scan512(sd, t);
    if (t < NBUK)
        cur[t]  = (sd[t]  - bucketTotal[t])  + colScan[j * NBUK + t];
    if (i2 < NBUK)
        cur[i2] = (sd[i2] - bucketTotal[i2]) + colScan[j * NBUK + i2];
    __syncthreads();
    int e0 = j * EPB;
    for (int e = e0 + t; e < e0 + EPB; e += 256){
        int s = src[e], d = dst[e];
        int pos = atomicAdd(&cur[d >> 8], 1);
        int2 v; v.x = s; v.y = d;
        ebuf[pos] = v;
    }
}

// ---------------- P4: per-bucket counting sort -> row_ptr, csr_src, dinv -------
__global__ __launch_bounds__(256) void k_p4(const int2* __restrict__ ebuf,
                                            const int* __restrict__ bucketTotal,
                                            int* __restrict__ row_ptr,
                                            int* __restrict__ csr_src,
                                            float* __restrict__ dinv)
{
    __shared__ int2 stash[MAXB];
    __shared__ int sdScan[512];
    __shared__ int bins[256];
    __shared__ int sd[256];
    int b = blockIdx.x, t = threadIdx.x;
    int i2 = t + 256;
    sdScan[t]  = (t  < NBUK) ? bucketTotal[t]  : 0;
    sdScan[i2] = (i2 < NBUK) ? bucketTotal[i2] : 0;
    __syncthreads();
    scan512(sdScan, t);
    int cntb = bucketTotal[b];
    int base = sdScan[b] - cntb;
    bool st = (cntb <= MAXB);
    bins[t] = 0;
    __syncthreads();
    for (int i = t; i < cntb; i += 256){
        int2 ed = ebuf[base + i];
        if (st) stash[i] = ed;
        atomicAdd(&bins[ed.y & 255], 1);
    }
    __syncthreads();
    int a0 = bins[t];
    sd[t] = a0;
    __syncthreads();
    for (int off = 1; off < 256; off <<= 1){
        int v = (t >= off) ? sd[t - off] : 0;
        __syncthreads();
        sd[t] += v;
        __syncthreads();
    }
    int pex = sd[t] - a0;
    int node = b * 256 + t;
    if (node < N_NODES){
        row_ptr[node] = base + pex;
        float d = (float)(a0 + 1);
        dinv[node]  = rsqrtf(d);
    }
    __syncthreads();
    bins[t] = pex;
    __syncthreads();
    for (int i = t; i < cntb; i += 256){
        int2 ed = st ? stash[i] : ebuf[base + i];
        int pos = atomicAdd(&bins[ed.y & 255], 1);
        csr_src[base + pos] = ed.x;
    }
}

// ---------------- MFMA GEMM: A staged via LDS, W prepacked, dinv-scaled out ----
// tbuf[row] = dinv[row] * (BN/ReLU(A[row]) @ W).
// mode 0: A is fp32, no BN (layer 0). mode 1: A is fp16 h, BN+ReLU on load.
__global__ __launch_bounds__(256) void k_gemm(const void* __restrict__ Ain,
                                              const unsigned int* __restrict__ wp,
                                              const float* __restrict__ scale,
                                              const float* __restrict__ shift,
                                              const float* __restrict__ dinv,
                                              __half* __restrict__ outh,
                                              int mode)
{
    __shared__ unsigned int lds32[WOFF + 128 * LSTR];   // 52224 B
    int tid = threadIdx.x;
    int rowBase = blockIdx.x * 64;

    if (mode == 0){
        const float* A = (const float*)Ain;
        #pragma unroll
        for (int rep = 0; rep < 8; rep++){
            int f  = rep * 256 + tid;
            int m  = f >> 5;
            int c4 = f & 31;
            int row = rowBase + m;
            if (row >= N_NODES) row = N_NODES - 1;
            float4 v = *(const float4*)(A + (size_t)row * D + c4 * 4);
            __half2 h0 = __floats2half2_rn(v.x, v.y);
            __half2 h1 = __floats2half2_rn(v.z, v.w);
            uint2 u; u.x = *(unsigned int*)&h0; u.y = *(unsigned int*)&h1;
            *(uint2*)&lds32[m * LSTR + 2 * c4] = u;
        }
    } else {
        const __half* A16 = (const __half*)Ain;
        #pragma unroll
        for (int rep = 0; rep < 4; rep++){
            int f  = rep * 256 + tid;
            int m  = f >> 4;
            int c8 = f & 15;
            int row = rowBase + m;
            if (row >= N_NODES) row = N_NODES - 1;
            uint4 v = *(const uint4*)(A16 + (size_t)row * D + c8 * 8);
            float4 sc0 = *(const float4*)(scale + c8 * 8);
            float4 sc1 = *(const float4*)(scale + c8 * 8 + 4);
            float4 sh0 = *(const float4*)(shift + c8 * 8);
            float4 sh1 = *(const float4*)(shift + c8 * 8 + 4);
            float2 f0 = __half22float2(*(__half2*)&v.x);
            float2 f1 = __half22float2(*(__half2*)&v.y);
            float2 f2 = __half22float2(*(__half2*)&v.z);
            float2 f3 = __half22float2(*(__half2*)&v.w);
            f0.x = relu_f(fmaf(f0.x, sc0.x, sh0.x));
            f0.y = relu_f(fmaf(f0.y, sc0.y, sh0.y));
            f1.x = relu_f(fmaf(f1.x, sc0.z, sh0.z));
            f1.y = relu_f(fmaf(f1.y, sc0.w, sh0.w));
            f2.x = relu_f(fmaf(f2.x, sc1.x, sh1.x));
            f2.y = relu_f(fmaf(f2.y, sc1.y, sh1.y));
            f3.x = relu_f(fmaf(f3.x, sc1.z, sh1.z));
            f3.y = relu_f(fmaf(f3.y, sc1.w, sh1.w));
            __half2 h0 = __floats2half2_rn(f0.x, f0.y);
            __half2 h1 = __floats2half2_rn(f1.x, f1.y);
            __half2 h2 = __floats2half2_rn(f2.x, f2.y);
            __half2 h3 = __floats2half2_rn(f3.x, f3.y);
            uint4 u;
            u.x = *(unsigned int*)&h0; u.y = *(unsigned int*)&h1;
            u.z = *(unsigned int*)&h2; u.w = *(unsigned int*)&h3;
            *(uint4*)&lds32[m * LSTR + 4 * c8] = u;
        }
    }
    {
        const uint4* gw = (const uint4*)wp;
        #pragma unroll
        for (int rep = 0; rep < 8; rep++){
            int f = rep * 256 + tid;
            int c = f >> 4;
            int q = f & 15;
            uint4 v = gw[f];
            *(uint4*)&lds32[WOFF + c * LSTR + 4 * q] = v;
        }
    }
    __syncthreads();

    int lane = tid & 63, wv = tid >> 6;
    int quad = lane >> 5;
    int ml   = (lane & 31) + (wv & 1) * 32;
    int cA   = (wv >> 1) * 64;
    int c0   = cA + (lane & 31);
    int c1   = c0 + 32;
    const unsigned int* aRow  = lds32 + ml * LSTR;
    const unsigned int* bRow0 = lds32 + WOFF + c0 * LSTR;
    const unsigned int* bRow1 = lds32 + WOFF + c1 * LSTR;
    floatx16 acc0 = {};
    floatx16 acc1 = {};
    #pragma unroll
    for (int ch = 0; ch < 8; ch++){
        int o = ch * 8 + quad * 4;
        half8 af = *(const half8*)(aRow  + o);
        half8 b0 = *(const half8*)(bRow0 + o);
        half8 b1 = *(const half8*)(bRow1 + o);
        acc0 = __builtin_amdgcn_mfma_f32_32x32x16_f16(af, b0, acc0, 0, 0, 0);
        acc1 = __builtin_amdgcn_mfma_f32_32x32x16_f16(af, b1, acc1, 0, 0, 0);
    }
    int rBase = rowBase + (wv & 1) * 32 + 4 * quad;
    #pragma unroll
    for (int r = 0; r < 16; r++){
        int outRow = rBase + (r & 3) + 8 * (r >> 2);
        if (outRow < N_NODES){
            float dv = dinv[outRow];
            outh[(size_t)outRow * D + c0] = __float2half(acc0[r] * dv);
            outh[(size_t)outRow * D + c1] = __float2half(acc1[r] * dv);
        }
    }
}

__device__ __forceinline__ void accum8(float* acc, uint4 v)
{
    float2 f0 = __half22float2(*(__half2*)&v.x);
    float2 f1 = __half22float2(*(__half2*)&v.y);
    float2 f2 = __half22float2(*(__half2*)&v.z);
    float2 f3 = __half22float2(*(__half2*)&v.w);
    acc[0] += f0.x; acc[1] += f0.y; acc[2] += f1.x; acc[3] += f1.y;
    acc[4] += f2.x; acc[5] += f2.y; acc[6] += f3.x; acc[7] += f3.y;
}

// ---------------- edge aggregation v6: 16-lane groups, 16B/lane gathers --------
// Wave = 4 groups x 16 lanes; group owns node i; lane q covers features
// [8q,8q+8). tbuf rows pre-scaled by dinv[src] -> unweighted sum; final scale
// by dinv[i] + bias. Output now fp16 (8 halves packed per lane). Stats in fp32
// regs (pre-rounding), 2 shfl_xor rounds, slot-scattered atomics.
__global__ __launch_bounds__(256) void k_agg(const __half* __restrict__ t,
                                             const int* __restrict__ row_ptr,
                                             const int* __restrict__ csr_src,
                                             const float* __restrict__ dinv,
                                             const float* __restrict__ bias,
                                             __half* __restrict__ outb,
                                             float* __restrict__ Spart,
                                             float* __restrict__ Qpart)
{
    __shared__ float ldsS[4][128];
    __shared__ float ldsQ[4][128];
    int tid  = threadIdx.x;
    int lane = tid & 63;
    int wv   = tid >> 6;
    int q    = lane & 15;          // feature slot
    int g    = lane >> 4;          // group 0..3
    const uint4* t4 = (const uint4*)t;
    uint4* out4 = (uint4*)outb;

    float4 bia = ((const float4*)bias)[2 * q];
    float4 bib = ((const float4*)bias)[2 * q + 1];

    float sa[8] = {0.f,0.f,0.f,0.f,0.f,0.f,0.f,0.f};
    float qa[8] = {0.f,0.f,0.f,0.f,0.f,0.f,0.f,0.f};

    int i0 = blockIdx.x * 32 + wv * 8 + g * 2;   // group covers 2 nodes

    for (int n = 0; n < 2; n++){
        int i  = i0 + n;
        int p  = row_ptr[i];
        int pe = row_ptr[i + 1];
        float acc[8];
        {   // self row (pre-scaled by dinv[i] already)
            uint4 v = t4[(size_t)i * 16 + q];
            float2 f0 = __half22float2(*(__half2*)&v.x);
            float2 f1 = __half22float2(*(__half2*)&v.y);
            float2 f2 = __half22float2(*(__half2*)&v.z);
            float2 f3 = __half22float2(*(__half2*)&v.w);
            acc[0] = f0.x; acc[1] = f0.y; acc[2] = f1.x; acc[3] = f1.y;
            acc[4] = f2.x; acc[5] = f2.y; acc[6] = f3.x; acc[7] = f3.y;
        }
        for (; p + 4 <= pe; p += 4){
            int s0 = csr_src[p],     s1 = csr_src[p + 1];
            int s2 = csr_src[p + 2], s3 = csr_src[p + 3];
            uint4 v0 = t4[(size_t)s0 * 16 + q];
            uint4 v1 = t4[(size_t)s1 * 16 + q];
            uint4 v2 = t4[(size_t)s2 * 16 + q];
            uint4 v3 = t4[(size_t)s3 * 16 + q];
            accum8(acc, v0); accum8(acc, v1); accum8(acc, v2); accum8(acc, v3);
        }
        for (; p < pe; ++p){
            int s = csr_src[p];
            uint4 v = t4[(size_t)s * 16 + q];
            accum8(acc, v);
        }
        float dvi = dinv[i];
        acc[0] = fmaf(acc[0], dvi, bia.x);
        acc[1] = fmaf(acc[1], dvi, bia.y);
        acc[2] = fmaf(acc[2], dvi, bia.z);
        acc[3] = fmaf(acc[3], dvi, bia.w);
        acc[4] = fmaf(acc[4], dvi, bib.x);
        acc[5] = fmaf(acc[5], dvi, bib.y);
        acc[6] = fmaf(acc[6], dvi, bib.z);
        acc[7] = fmaf(acc[7], dvi, bib.w);
        __half2 o0 = __floats2half2_rn(acc[0], acc[1]);
        __half2 o1 = __floats2half2_rn(acc[2], acc[3]);
        __half2 o2 = __floats2half2_rn(acc[4], acc[5]);
        __half2 o3 = __floats2half2_rn(acc[6], acc[7]);
        uint4 ov;
        ov.x = *(unsigned int*)&o0; ov.y = *(unsigned int*)&o1;
        ov.z = *(unsigned int*)&o2; ov.w = *(unsigned int*)&o3;
        out4[(size_t)i * 16 + q] = ov;
        #pragma unroll
        for (int k = 0; k < 8; k++){
            sa[k] += acc[k];
            qa[k]  = fmaf(acc[k], acc[k], qa[k]);
        }
    }

    // combine the 4 groups' per-feature stats within the wave
    #pragma unroll
    for (int k = 0; k < 8; k++){
        sa[k] += __shfl_xor(sa[k], 16);
        sa[k] += __shfl_xor(sa[k], 32);
        qa[k] += __shfl_xor(qa[k], 16);
        qa[k] += __shfl_xor(qa[k], 32);
    }
    if (g == 0){
        #pragma unroll
        for (int k = 0; k < 8; k++){
            ldsS[wv][8 * q + k] = sa[k];
            ldsQ[wv][8 * q + k] = qa[k];
        }
    }
    __syncthreads();
    int slotBase = (blockIdx.x & (NSLOT - 1)) * 128;
    if (tid < 128){
        float s = ldsS[0][tid] + ldsS[1][tid] + ldsS[2][tid] + ldsS[3][tid];
        atomicAdd(&Spart[slotBase + tid], s);
    } else {
        int f = tid - 128;
        float qv = ldsQ[0][f] + ldsQ[1][f] + ldsQ[2][f] + ldsQ[3][f];
        atomicAdd(&Qpart[slotBase + f], qv);
    }
}

// ---------------- finalize: reduce NSLOT slots -> scale/shift (1 block) --------
__global__ __launch_bounds__(256) void k_fin2(const float* __restrict__ Spart,
                                              const float* __restrict__ Qpart,
                                              const float* __restrict__ gamma,
                                              const float* __restrict__ beta,
                                              float* __restrict__ sc,
                                              float* __restrict__ sh)
{
    int t = threadIdx.x;
    int f = t & 127;
    const float* src = (t < 128) ? Spart : Qpart;
    float acc = 0.f;
    for (int s2 = 0; s2 < NSLOT; s2++)
        acc += src[s2 * 128 + f];
    __shared__ float red[256];
    red[t] = acc;
    __syncthreads();
    if (t < 128){
        float Sv = red[t];
        float Qv = red[t + 128];
        float mean = Sv * (1.0f / N_NODES);
        float var  = fmaxf(Qv * (1.0f / N_NODES) - mean * mean, 0.0f);
        float inv  = rsqrtf(var + EPSV);
        float gm = gamma[f] * inv;
        sc[f] = gm;
        sh[f] = beta[f] - mean * gm;
    }
}

// ---------------- TAIL: per-graph BN+ReLU+mean + MLP head (one block/graph) ----
__global__ __launch_bounds__(256) void k_tail(const __half* __restrict__ h,
                                              const int* __restrict__ gstart,
                                              const float* __restrict__ sc,
                                              const float* __restrict__ sh,
                                              const float* __restrict__ W1,
                                              const float* __restrict__ b1,
                                              const float* __restrict__ W2,
                                              const float* __restrict__ b2,
                                              float* __restrict__ out)
{
    __shared__ float part[256];
    __shared__ float z[128];
    __shared__ float red[128];
    int g = blockIdx.x;
    int tid = threadIdx.x;
    int f = tid & 127;
    int hf = tid >> 7;                // 0/1: row-parity split
    int s0 = gstart[g], s1 = gstart[g + 1];
    float scv = sc[f], shv = sh[f];
    float acc = 0.f;
    for (int i = s0 + hf; i < s1; i += 2)
        acc += relu_f(fmaf(__half2float(h[(size_t)i * D + f]), scv, shv));
    part[tid] = acc;
    __syncthreads();
    if (tid < 128){
        float c = fmaxf((float)(s1 - s0), 1.0f);
        z[f] = (part[f] + part[f + 128]) / c;
    }
    __syncthreads();
    // head GEMV: thread (f,hf) covers k in [hf*64, hf*64+64)
    float a = 0.f;
    int k0 = hf * 64;
    #pragma unroll 8
    for (int k = k0; k < k0 + 64; k++)
        a = fmaf(z[k], W1[k * D + f], a);
    part[tid] = a;
    __syncthreads();
    if (tid < 128){
        float av = relu_f(part[f] + part[f + 128] + b1[f]);
        red[f] = av * W2[f];
    }
    __syncthreads();
    for (int s2 = 64; s2 > 0; s2 >>= 1){
        if (tid < s2) red[tid] += red[tid + s2];
        __syncthreads();
    }
    if (tid == 0) out[g] = red[0] + b2[0];
}

extern "C" void kernel_launch(void* const* d_in, const int* in_sizes, int n_in,
                              void* d_out, int out_size, void* d_ws, size_t ws_size,
                              hipStream_t stream)
{
    const float* x      = (const float*)d_in[0];
    const int*   ei     = (const int*)d_in[1];
    const int*   batch  = (const int*)d_in[2];
    const float* Ws     = (const float*)d_in[3];
    const float* bs     = (const float*)d_in[4];
    const float* gammas = (const float*)d_in[5];
    const float* betas  = (const float*)d_in[6];
    const float* W1     = (const float*)d_in[7];
    const float* b1     = (const float*)d_in[8];
    const float* W2     = (const float*)d_in[9];
    const float* b2     = (const float*)d_in[10];
    float* out = (float*)d_out;

    const int* src = ei;
    const int* dst = ei + N_EDGES;

    char* w = (char*)d_ws;
    size_t off = 0;
    auto alloc = [&](size_t bytes) -> void* {
        void* p = w + off;
        off += (bytes + 255) & ~(size_t)255;
        return p;
    };
    int*   row_ptr     = (int*)  alloc((size_t)(N_NODES + 1) * 4);
    float* dinv        = (float*)alloc((size_t)N_NODES * 4);
    int*   csr_src     = (int*)  alloc((size_t)N_EDGES * 4);
    int*   blockHist   = (int*)  alloc((size_t)NBLK * NBUK * 4);
    int*   colScan     = (int*)  alloc((size_t)NBLK * NBUK * 4);
    int*   bucketTotal = (int*)  alloc((size_t)NBUK * 4);
    unsigned int* wpack = (unsigned int*)alloc((size_t)3 * 128 * 64 * 4);
    int*   gstart      = (int*)  alloc((size_t)(N_GRAPHS + 1) * 4);
    size_t zoff = off;                       // --- zero-span start ---
    float* stats       = (float*)alloc((size_t)3 * 2 * NSLOT * 128 * 4); // per layer: Spart, Qpart
    size_t zend = off;                       // --- zero-span end ---
    float* ssh         = (float*)alloc(3 * 256 * 4);   // per layer: scale, shift
    __half* tbuf       = (__half*)alloc((size_t)N_NODES * 128 * 2);  // fp16 gather table (dinv-scaled)
    __half* hbuf       = (__half*)alloc((size_t)N_NODES * 128 * 2);  // fp16 h (pre-BN)
    if (off > ws_size) return;

    // alias scratch (consumed before tbuf is first written; stream-ordered)
    int2* ebuf = (int2*)tbuf;    // 6.4 MB < 25.6 MB

    k_front<<<NBLK + 96, 256, 0, stream>>>(dst, blockHist, Ws, wpack,
                                           (unsigned int*)(w + zoff),
                                           (int)((zend - zoff) >> 2),
                                           batch, gstart, row_ptr);
    k_p2a<<<NBUK, 256, 0, stream>>>(blockHist, colScan, bucketTotal);
    k_p3 <<<NBLK, 256, 0, stream>>>(src, dst, colScan, bucketTotal, ebuf);
    k_p4 <<<NBUK, 256, 0, stream>>>(ebuf, bucketTotal, row_ptr, csr_src, dinv);

    const void* curIn = (const void*)x;
    for (int l = 0; l < 3; l++){
        float* Sp = stats + (size_t)l * 2 * NSLOT * 128;
        float* Qp = Sp + NSLOT * 128;
        k_gemm<<<(N_NODES + 63) / 64, 256, 0, stream>>>(
            curIn, wpack + l * 8192,
            l ? ssh + (l - 1) * 256       : nullptr,
            l ? ssh + (l - 1) * 256 + 128 : nullptr,
            dinv, tbuf, l ? 1 : 0);
        k_agg<<<N_NODES / 32, 256, 0, stream>>>(
            tbuf, row_ptr, csr_src, dinv,
            bs + l * 128, hbuf, Sp, Qp);
        k_fin2<<<1, 256, 0, stream>>>(
            Sp, Qp, gammas + l * 128, betas + l * 128,
            ssh + l * 256, ssh + l * 256 + 128);
        curIn = (const void*)hbuf;
    }

    k_tail<<<N_GRAPHS, 256, 0, stream>>>(hbuf, gstart,
                                         ssh + 2 * 256, ssh + 2 * 256 + 128,
                                         W1, b1, W2, b2, out);
}